// Round 9
// baseline (331.585 us; speedup 1.0000x reference)
//
#include <hip/hip_runtime.h>
#include <cstdint>
#include <cstddef>

#define I_DIM 1024
#define O_DIM 1024
#define B_DIM 128
#define T_DIM 100
#define PANEL 32768  // fragment-tiled panel stride (ushorts) = 64q*64lane*8
#define QSTep 512    // per-q stride (ushorts) = 64 lanes * 8

typedef __attribute__((ext_vector_type(8))) __bf16 bf16x8;
typedef __attribute__((ext_vector_type(16))) float f32x16;

// Workgroup barrier draining only LDS ops (lgkmcnt=0); global loads/stores
// stay in flight. simm16 = vm[3:0]=0xF | exp=7<<4 | lgkm=0<<8 | vm[5:4]=3<<14.
__device__ __forceinline__ void wg_barrier_lgkm() {
  __asm__ volatile("" ::: "memory");
  __builtin_amdgcn_s_waitcnt(0xC07F);
  __builtin_amdgcn_s_barrier();
  __asm__ volatile("" ::: "memory");
}

__device__ __forceinline__ unsigned short bf16rn(float x) {
  unsigned u = __float_as_uint(x);
  unsigned r = u + 0x7FFFu + ((u >> 16) & 1u);
  return (unsigned short)(r >> 16);
}
__device__ __forceinline__ void split2(float x, unsigned short& h,
                                       unsigned short& l) {
  h = bf16rn(x);
  float hf = __uint_as_float(((unsigned)h) << 16);
  l = bf16rn(x - hf);
}

// ---------------------------------------------------------------------------
// prep: WGs 0..255 = split_wT (+norm partials); WGs 256..1855 = xsplit.
// Layouts identical to R6/R7/R8 (validated).
// ---------------------------------------------------------------------------
__global__ __launch_bounds__(256) void prep_kernel(
    const float* __restrict__ w, const float* __restrict__ x,
    unsigned short* __restrict__ wTth, unsigned short* __restrict__ wTtl,
    unsigned short* __restrict__ xth, unsigned short* __restrict__ xtl,
    double* __restrict__ normpart) {
  __shared__ float tile[64][65];
  __shared__ double red[4][64];
  const int id = blockIdx.x;
  const int tid = threadIdx.x;
  if (id < 256) {  // ---- split_wT ----
    const int a0 = (id >> 4) * 64, o0 = (id & 15) * 64;
    const int tr = tid >> 4, tc4 = (tid & 15) * 4;
#pragma unroll
    for (int rr = 0; rr < 64; rr += 16) {
      float4 v = *(const float4*)&w[(size_t)(a0 + tr + rr) * O_DIM + o0 + tc4];
      tile[tr + rr][tc4 + 0] = v.x;
      tile[tr + rr][tc4 + 1] = v.y;
      tile[tr + rr][tc4 + 2] = v.z;
      tile[tr + rr][tc4 + 3] = v.w;
    }
    __syncthreads();
    {
      const int ol = tid & 63, seg = tid >> 6;
      double s = 0.0;
#pragma unroll
      for (int i = 0; i < 16; ++i) {
        double v = (double)tile[seg * 16 + i][ol];
        s += v * v;
      }
      red[seg][ol] = s;
    }
    const int q = (a0 >> 4) + (tc4 >> 4);
    const int kh = (tc4 >> 3) & 1;
    const int inner = tc4 & 7;
#pragma unroll
    for (int rr = 0; rr < 64; rr += 16) {
      int o = o0 + tr + rr;
      unsigned short hh[4], ll[4];
#pragma unroll
      for (int j = 0; j < 4; ++j) split2(tile[tc4 + j][tr + rr], hh[j], ll[j]);
      int l = (o & 31) + 32 * kh;
      size_t base = ((size_t)(o >> 5) * PANEL) + (size_t)q * QSTep +
                    (size_t)l * 8 + inner;
      *(ushort4*)&wTth[base] = make_ushort4(hh[0], hh[1], hh[2], hh[3]);
      *(ushort4*)&wTtl[base] = make_ushort4(ll[0], ll[1], ll[2], ll[3]);
    }
    __syncthreads();
    if (tid < 64)
      normpart[(size_t)(a0 >> 6) * O_DIM + o0 + tid] =
          red[0][tid] + red[1][tid] + red[2][tid] + red[3][tid];
  } else {  // ---- xsplit: 4 WGs per 32-row panel ----
    const int p = (id - 256) >> 2, sub = (id - 256) & 3;
    const int wq = tid >> 6, lane = tid & 63;
    const int row = lane & 31, kh = lane >> 5;
    const float* src = x + (size_t)(p * 32 + row) * I_DIM + kh * 8;
#pragma unroll
    for (int i = sub * 4; i < sub * 4 + 4; ++i) {
      const int q = i * 4 + wq;
      const float* s = src + q * 16;
      float4 v0 = *(const float4*)(s);
      float4 v1 = *(const float4*)(s + 4);
      unsigned short h[8], l[8];
      split2(v0.x, h[0], l[0]);
      split2(v0.y, h[1], l[1]);
      split2(v0.z, h[2], l[2]);
      split2(v0.w, h[3], l[3]);
      split2(v1.x, h[4], l[4]);
      split2(v1.y, h[5], l[5]);
      split2(v1.z, h[6], l[6]);
      split2(v1.w, h[7], l[7]);
      size_t base = ((size_t)p * PANEL) + (size_t)q * QSTep + (size_t)lane * 8;
      *(ushort4*)&xth[base] = make_ushort4(h[0], h[1], h[2], h[3]);
      *(ushort4*)&xth[base + 4] = make_ushort4(h[4], h[5], h[6], h[7]);
      *(ushort4*)&xtl[base] = make_ushort4(l[0], l[1], l[2], l[3]);
      *(ushort4*)&xtl[base + 4] = make_ushort4(l[4], l[5], l[6], l[7]);
    }
  }
}

// ---------------------------------------------------------------------------
// gemm_fused: 512 threads = 8 waves/WG. y<100 -> hgemm WG tile 128x128
// (R6's low-traffic footprint) with 8-wave residency (R7-beating occupancy:
// 800 WGs x 8 waves = 25 waves/CU). Wave tile 64x32, per-q 6 loads : 6
// MFMAs, distance-1 prefetch (R7-validated shape; R8's pair pipeline was
// compiler-defeated and is reverted). y in [100,108) -> mbuild, same
// geometry, A=B=wTt, epilogue with beta*v. Zero LDS, zero barriers.
// Per-acc MFMA order (q asc; hh,hl,lh) unchanged -> bit-identical h, M.
// ---------------------------------------------------------------------------
__global__ __launch_bounds__(512, 5) void gemm_fused(
    const unsigned short* __restrict__ xth,
    const unsigned short* __restrict__ xtl,
    const unsigned short* __restrict__ wTth,
    const unsigned short* __restrict__ wTtl, const float* __restrict__ v,
    const float* __restrict__ beta_p, float* __restrict__ h,
    float* __restrict__ M) {
  const int tid = threadIdx.x;
  const int wv = tid >> 6, lane = tid & 63;
  const int wm = wv >> 2, wn = wv & 3;  // 2 x 4 waves: 64-row x 32-col tiles
  const int lm = lane & 31, lkh = lane >> 5;
  const bool is_h = blockIdx.y < 100;
  const int rbase = is_h ? (int)blockIdx.y * 128 : ((int)blockIdx.y - 100) * 128;
  const int cbase = (int)blockIdx.x * 128;
  const unsigned short* Ah_src = is_h ? xth : wTth;
  const unsigned short* Al_src = is_h ? xtl : wTtl;

  f32x16 acc[2];
#pragma unroll
  for (int a = 0; a < 2; ++a)
#pragma unroll
    for (int e = 0; e < 16; ++e) acc[a][e] = 0.f;

  const unsigned short *pah[2], *pal[2], *pbh, *pbl;
#pragma unroll
  for (int mt = 0; mt < 2; ++mt) {
    size_t offA =
        ((size_t)((rbase >> 5) + wm * 2 + mt) * PANEL) + (size_t)lane * 8;
    pah[mt] = Ah_src + offA;
    pal[mt] = Al_src + offA;
  }
  {
    size_t offB = ((size_t)((cbase >> 5) + wn) * PANEL) + (size_t)lane * 8;
    pbh = wTth + offB;
    pbl = wTtl + offB;
  }
  bf16x8 fah[2][2], fal[2][2], fbh[2], fbl[2];  // [buf][mt] / [buf]
#pragma unroll
  for (int mt = 0; mt < 2; ++mt) {
    fah[0][mt] = *(const bf16x8*)(pah[mt]);
    fal[0][mt] = *(const bf16x8*)(pal[mt]);
  }
  fbh[0] = *(const bf16x8*)(pbh);
  fbl[0] = *(const bf16x8*)(pbl);
#pragma unroll 2
  for (int q = 0; q < 64; ++q) {
    const int cb = q & 1;
    if (q < 63) {
      size_t d = (size_t)(q + 1) * QSTep;
#pragma unroll
      for (int mt = 0; mt < 2; ++mt) {
        fah[cb ^ 1][mt] = *(const bf16x8*)(pah[mt] + d);
        fal[cb ^ 1][mt] = *(const bf16x8*)(pal[mt] + d);
      }
      fbh[cb ^ 1] = *(const bf16x8*)(pbh + d);
      fbl[cb ^ 1] = *(const bf16x8*)(pbl + d);
    }
#pragma unroll
    for (int mt = 0; mt < 2; ++mt)
      acc[mt] = __builtin_amdgcn_mfma_f32_32x32x16_bf16(fah[cb][mt], fbh[cb],
                                                        acc[mt], 0, 0, 0);
#pragma unroll
    for (int mt = 0; mt < 2; ++mt)
      acc[mt] = __builtin_amdgcn_mfma_f32_32x32x16_bf16(fah[cb][mt], fbl[cb],
                                                        acc[mt], 0, 0, 0);
#pragma unroll
    for (int mt = 0; mt < 2; ++mt)
      acc[mt] = __builtin_amdgcn_mfma_f32_32x32x16_bf16(fal[cb][mt], fbh[cb],
                                                        acc[mt], 0, 0, 0);
  }
  const int col = cbase + wn * 32 + lm;
  if (is_h) {
#pragma unroll
    for (int mt = 0; mt < 2; ++mt)
#pragma unroll
      for (int r = 0; r < 16; ++r) {
        int row = rbase + wm * 64 + mt * 32 + (r & 3) + 8 * (r >> 2) + 4 * lkh;
        h[(size_t)row * O_DIM + col] = acc[mt][r];
      }
  } else {
    const float beta = beta_p[0];
    const float ombeta = 1.0f - beta;
#pragma unroll
    for (int mt = 0; mt < 2; ++mt)
#pragma unroll
      for (int r = 0; r < 16; ++r) {
        int row = rbase + wm * 64 + mt * 32 + (r & 3) + 8 * (r >> 2) + 4 * lkh;
        M[(size_t)row * O_DIM + col] =
            ombeta * v[(size_t)row * O_DIM + col] - beta * acc[mt][r];
      }
  }
}

// ---------------------------------------------------------------------------
// Scan (R8-validated): contiguous neurons/thread, float4 h/out/M accesses,
// lgkm-only barrier per step, folded finalize via device done counter.
// ---------------------------------------------------------------------------
__global__ __launch_bounds__(256) void scan_kernel(
    const float* __restrict__ h, const float* __restrict__ M,
    const double* __restrict__ normpart, const float* __restrict__ bvec,
    const float* __restrict__ beta_p, float* __restrict__ out,
    int* __restrict__ wgcnt, int* __restrict__ done) {
  __shared__ unsigned short wlist[2][4][256];
  __shared__ int wcnt[2][4];
  __shared__ int reds[128];
  __shared__ int lastflag;
  const int b = blockIdx.x, tid = threadIdx.x;
  const int wv = tid >> 6;
  const int ob4 = tid * 4;
  const double beta = (double)beta_p[0];
  const double ombeta = 1.0 - beta;
  double mem[4] = {0.0, 0.0, 0.0, 0.0};
  double inv[4], bth[4];
#pragma unroll
  for (int j = 0; j < 4; ++j) {
    double s = 0.0;
#pragma unroll
    for (int g = 0; g < 16; ++g) s += normpart[(size_t)g * O_DIM + ob4 + j];
    inv[j] = 1.0 / (s + 1e-8);
    bth[j] = (double)bvec[ob4 + j];
  }
  if (tid < 8) wcnt[tid >> 2][tid & 3] = 0;
  __syncthreads();
  const float* hb = h + (size_t)b * T_DIM * O_DIM;
  float* obp = out + (size_t)b * T_DIM * O_DIM;
  float4 hv0 = *(const float4*)&hb[ob4];
  float4 hv1 = *(const float4*)&hb[O_DIM + ob4];
  for (int t = 0; t < T_DIM; ++t) {
    const int p = t & 1, np = p ^ 1;
    float4 hv2 = make_float4(0.f, 0.f, 0.f, 0.f);
    if (t + 2 < T_DIM) hv2 = *(const float4*)&hb[(size_t)(t + 2) * O_DIM + ob4];
    double lat[4] = {0.0, 0.0, 0.0, 0.0};
    const int ks = wcnt[p][0] + wcnt[p][1] + wcnt[p][2] + wcnt[p][3];
    if (ks) {
#pragma unroll
      for (int w = 0; w < 4; ++w) {
        const int kw = wcnt[p][w];
        for (int n = 0; n < kw; ++n) {
          const int i = wlist[p][w][n];
          float4 m = *(const float4*)&M[(size_t)i * O_DIM + ob4];
          lat[0] += (double)m.x;
          lat[1] += (double)m.y;
          lat[2] += (double)m.z;
          lat[3] += (double)m.w;
        }
      }
    }
    const float hvv[4] = {hv0.x, hv0.y, hv0.z, hv0.w};
    float os[4];
    unsigned cur = 0;
#pragma unroll
    for (int j = 0; j < 4; ++j) {
      mem[j] = mem[j] * beta + (double)hvv[j] * ombeta + lat[j];
      double mthr = mem[j] * inv[j] - bth[j];
      bool s = mthr > 0.0;
      os[j] = s ? 1.0f : 0.0f;
      unsigned long long mask = __ballot(s);
      if (s) {
        unsigned below = __builtin_amdgcn_mbcnt_lo((unsigned)mask, 0);
        below = __builtin_amdgcn_mbcnt_hi((unsigned)(mask >> 32), below);
        wlist[np][wv][cur + below] = (unsigned short)(ob4 + j);
      }
      cur += (unsigned)__popcll(mask);
    }
    *(float4*)&obp[(size_t)t * O_DIM + ob4] =
        make_float4(os[0], os[1], os[2], os[3]);
    hv0 = hv1;
    hv1 = hv2;
    if ((tid & 63) == 0) wcnt[np][wv] = (int)cur;
    wg_barrier_lgkm();
    if (tid == 0)
      wgcnt[b * T_DIM + t] =
          wcnt[np][0] + wcnt[np][1] + wcnt[np][2] + wcnt[np][3];
  }
  // ---- folded finalize: last WG reduces all wgcnt ----
  __threadfence();
  if (tid == 0) {
    int old = atomicAdd(done, 1);
    lastflag = (old == B_DIM - 1) ? 1 : 0;
  }
  __syncthreads();
  if (lastflag) {
    __threadfence();
    int s = 0;
    if (tid < T_DIM) {
      for (int bb = 0; bb < B_DIM; ++bb) s += wgcnt[bb * T_DIM + tid];
    }
    if (tid < 128) reds[tid] = (tid < T_DIM) ? s : 0;
    __syncthreads();
    if (tid == 0) {
      long long total = 0;
      int mx = 0;
      for (int i = 0; i < T_DIM; ++i) {
        total += reds[i];
        if (reds[i] > mx) mx = reds[i];
      }
      const double N = (double)B_DIM * T_DIM * O_DIM;
      out[(size_t)B_DIM * T_DIM * O_DIM] = (float)(0.5 * (double)total / N);
      out[(size_t)B_DIM * T_DIM * O_DIM + 1] =
          (float)((double)mx / (double)(B_DIM * O_DIM));
    }
  }
}

extern "C" void kernel_launch(void* const* d_in, const int* in_sizes, int n_in,
                              void* d_out, int out_size, void* d_ws,
                              size_t ws_size, hipStream_t stream) {
  const float* x = (const float*)d_in[0];
  const float* w = (const float*)d_in[1];
  const float* v = (const float*)d_in[2];
  const float* beta = (const float*)d_in[3];
  const float* b = (const float*)d_in[4];
  float* out = (float*)d_out;

  char* ws = (char*)d_ws;
  const size_t OFF_M = 0;            // 4 MB
  const size_t OFF_H = 4194304;      // 50 MB
  const size_t OFF_WTH = 56623104;   // 2 MB
  const size_t OFF_WTL = 58720256;   // 2 MB
  const size_t OFF_NP = 60817408;    // 128 KB normpart
  const size_t OFF_DONE = 60948480;  // 512 B done counter
  const size_t OFF_XTH = 60948992;   // 25 MB
  const size_t OFF_XTL = 87163392;   // 25 MB -> end 113377792 (fits, proven)
  float* M = (float*)(ws + OFF_M);
  float* h = (float*)(ws + OFF_H);
  unsigned short* wTth = (unsigned short*)(ws + OFF_WTH);
  unsigned short* wTtl = (unsigned short*)(ws + OFF_WTL);
  double* normpart = (double*)(ws + OFF_NP);
  int* done = (int*)(ws + OFF_DONE);
  unsigned short* xth = (unsigned short*)(ws + OFF_XTH);
  unsigned short* xtl = (unsigned short*)(ws + OFF_XTL);
  int* wgcnt = (int*)(ws + OFF_XTH);  // reuses dead xt region

  hipMemsetAsync(done, 0, 512, stream);
  hipLaunchKernelGGL(prep_kernel, dim3(1856), dim3(256), 0, stream, w, x, wTth,
                     wTtl, xth, xtl, normpart);
  hipLaunchKernelGGL(gemm_fused, dim3(8, 108), dim3(512), 0, stream, xth, xtl,
                     wTth, wTtl, v, beta, h, M);
  hipLaunchKernelGGL(scan_kernel, dim3(128), dim3(256), 0, stream, h, M,
                     normpart, b, beta, out, wgcnt, done);
}

// Round 10
// 315.096 us; speedup vs baseline: 1.0523x; 1.0523x over previous
//
#include <hip/hip_runtime.h>
#include <cstdint>
#include <cstddef>

#define I_DIM 1024
#define O_DIM 1024
#define B_DIM 128
#define T_DIM 100
#define PANEL 32768  // fragment-tiled panel stride (ushorts) = 64q*64lane*8
#define QSTep 512    // per-q stride (ushorts) = 64 lanes * 8

typedef __attribute__((ext_vector_type(8))) __bf16 bf16x8;
typedef __attribute__((ext_vector_type(16))) float f32x16;

__device__ __forceinline__ unsigned short bf16rn(float x) {
  unsigned u = __float_as_uint(x);
  unsigned r = u + 0x7FFFu + ((u >> 16) & 1u);
  return (unsigned short)(r >> 16);
}
__device__ __forceinline__ void split2(float x, unsigned short& h,
                                       unsigned short& l) {
  h = bf16rn(x);
  float hf = __uint_as_float(((unsigned)h) << 16);
  l = bf16rn(x - hf);
}

// ---------------------------------------------------------------------------
// prep: WGs 0..255 = split_wT (+norm partials); WGs 256..1855 = xsplit.
// Layouts identical to R6..R9 (validated).
// ---------------------------------------------------------------------------
__global__ __launch_bounds__(256) void prep_kernel(
    const float* __restrict__ w, const float* __restrict__ x,
    unsigned short* __restrict__ wTth, unsigned short* __restrict__ wTtl,
    unsigned short* __restrict__ xth, unsigned short* __restrict__ xtl,
    double* __restrict__ normpart) {
  __shared__ float tile[64][65];
  __shared__ double red[4][64];
  const int id = blockIdx.x;
  const int tid = threadIdx.x;
  if (id < 256) {  // ---- split_wT ----
    const int a0 = (id >> 4) * 64, o0 = (id & 15) * 64;
    const int tr = tid >> 4, tc4 = (tid & 15) * 4;
#pragma unroll
    for (int rr = 0; rr < 64; rr += 16) {
      float4 v = *(const float4*)&w[(size_t)(a0 + tr + rr) * O_DIM + o0 + tc4];
      tile[tr + rr][tc4 + 0] = v.x;
      tile[tr + rr][tc4 + 1] = v.y;
      tile[tr + rr][tc4 + 2] = v.z;
      tile[tr + rr][tc4 + 3] = v.w;
    }
    __syncthreads();
    {
      const int ol = tid & 63, seg = tid >> 6;
      double s = 0.0;
#pragma unroll
      for (int i = 0; i < 16; ++i) {
        double v = (double)tile[seg * 16 + i][ol];
        s += v * v;
      }
      red[seg][ol] = s;
    }
    const int q = (a0 >> 4) + (tc4 >> 4);
    const int kh = (tc4 >> 3) & 1;
    const int inner = tc4 & 7;
#pragma unroll
    for (int rr = 0; rr < 64; rr += 16) {
      int o = o0 + tr + rr;
      unsigned short hh[4], ll[4];
#pragma unroll
      for (int j = 0; j < 4; ++j) split2(tile[tc4 + j][tr + rr], hh[j], ll[j]);
      int l = (o & 31) + 32 * kh;
      size_t base = ((size_t)(o >> 5) * PANEL) + (size_t)q * QSTep +
                    (size_t)l * 8 + inner;
      *(ushort4*)&wTth[base] = make_ushort4(hh[0], hh[1], hh[2], hh[3]);
      *(ushort4*)&wTtl[base] = make_ushort4(ll[0], ll[1], ll[2], ll[3]);
    }
    __syncthreads();
    if (tid < 64)
      normpart[(size_t)(a0 >> 6) * O_DIM + o0 + tid] =
          red[0][tid] + red[1][tid] + red[2][tid] + red[3][tid];
  } else {  // ---- xsplit: 4 WGs per 32-row panel ----
    const int p = (id - 256) >> 2, sub = (id - 256) & 3;
    const int wq = tid >> 6, lane = tid & 63;
    const int row = lane & 31, kh = lane >> 5;
    const float* src = x + (size_t)(p * 32 + row) * I_DIM + kh * 8;
#pragma unroll
    for (int i = sub * 4; i < sub * 4 + 4; ++i) {
      const int q = i * 4 + wq;
      const float* s = src + q * 16;
      float4 v0 = *(const float4*)(s);
      float4 v1 = *(const float4*)(s + 4);
      unsigned short h[8], l[8];
      split2(v0.x, h[0], l[0]);
      split2(v0.y, h[1], l[1]);
      split2(v0.z, h[2], l[2]);
      split2(v0.w, h[3], l[3]);
      split2(v1.x, h[4], l[4]);
      split2(v1.y, h[5], l[5]);
      split2(v1.z, h[6], l[6]);
      split2(v1.w, h[7], l[7]);
      size_t base = ((size_t)p * PANEL) + (size_t)q * QSTep + (size_t)lane * 8;
      *(ushort4*)&xth[base] = make_ushort4(h[0], h[1], h[2], h[3]);
      *(ushort4*)&xth[base + 4] = make_ushort4(h[4], h[5], h[6], h[7]);
      *(ushort4*)&xtl[base] = make_ushort4(l[0], l[1], l[2], l[3]);
      *(ushort4*)&xtl[base + 4] = make_ushort4(l[4], l[5], l[6], l[7]);
    }
  }
}

// ---------------------------------------------------------------------------
// gemm_fused: 256 thr = 4 waves (2x2), WAVE tile 64x64 (2x2 32x32 accs):
// per q = 8 loads : 12 MFMAs -> L1-port ceiling rises 25%->37.5% (the
// R6-R9 invariant: MfmaUtil pinned ~25% by 1:1 load:MFMA through the
// shared per-CU L1). WG tile 128x128. ids 0..799 = hgemm with XCD swizzle
// (y=id%100: a row-panel's column blocks land on <=2 XCDs -> A reuse in
// L2); ids 800..863 = mbuild. Zero LDS/barriers. Per-acc MFMA order
// (q asc; hh,hl,lh) unchanged -> bit-identical h, M.
// ---------------------------------------------------------------------------
__global__ __launch_bounds__(256, 3) void gemm_fused(
    const unsigned short* __restrict__ xth,
    const unsigned short* __restrict__ xtl,
    const unsigned short* __restrict__ wTth,
    const unsigned short* __restrict__ wTtl, const float* __restrict__ v,
    const float* __restrict__ beta_p, float* __restrict__ h,
    float* __restrict__ M) {
  const int id = blockIdx.x;
  const int tid = threadIdx.x;
  const int wv = tid >> 6, lane = tid & 63;
  const int wm = wv >> 1, wn = wv & 1;
  const int lm = lane & 31, lkh = lane >> 5;
  const bool is_h = id < 800;
  int rbase, cbase;
  const unsigned short *Ah_src, *Al_src;
  if (is_h) {
    rbase = (id % 100) * 128;  // swizzle: same row-panel -> <=2 XCDs
    cbase = (id / 100) * 128;
    Ah_src = xth;
    Al_src = xtl;
  } else {
    rbase = ((id - 800) >> 3) * 128;
    cbase = ((id - 800) & 7) * 128;
    Ah_src = wTth;
    Al_src = wTtl;
  }
  f32x16 acc[2][2];
#pragma unroll
  for (int a = 0; a < 2; ++a)
#pragma unroll
    for (int b = 0; b < 2; ++b)
#pragma unroll
      for (int e = 0; e < 16; ++e) acc[a][b][e] = 0.f;
  const unsigned short *pah[2], *pal[2], *pbh[2], *pbl[2];
#pragma unroll
  for (int t = 0; t < 2; ++t) {
    size_t offA =
        ((size_t)((rbase >> 5) + wm * 2 + t) * PANEL) + (size_t)lane * 8;
    size_t offB =
        ((size_t)((cbase >> 5) + wn * 2 + t) * PANEL) + (size_t)lane * 8;
    pah[t] = Ah_src + offA;
    pal[t] = Al_src + offA;
    pbh[t] = wTth + offB;
    pbl[t] = wTtl + offB;
  }
  bf16x8 fah[2][2], fal[2][2], fbh[2][2], fbl[2][2];  // [buf][tile]
#pragma unroll
  for (int t = 0; t < 2; ++t) {
    fah[0][t] = *(const bf16x8*)(pah[t]);
    fal[0][t] = *(const bf16x8*)(pal[t]);
    fbh[0][t] = *(const bf16x8*)(pbh[t]);
    fbl[0][t] = *(const bf16x8*)(pbl[t]);
  }
#pragma unroll 2
  for (int q = 0; q < 64; ++q) {
    const int cb = q & 1;
    if (q < 63) {
      size_t d = (size_t)(q + 1) * QSTep;
#pragma unroll
      for (int t = 0; t < 2; ++t) {
        fah[cb ^ 1][t] = *(const bf16x8*)(pah[t] + d);
        fal[cb ^ 1][t] = *(const bf16x8*)(pal[t] + d);
        fbh[cb ^ 1][t] = *(const bf16x8*)(pbh[t] + d);
        fbl[cb ^ 1][t] = *(const bf16x8*)(pbl[t] + d);
      }
    }
#pragma unroll
    for (int mt = 0; mt < 2; ++mt)
#pragma unroll
      for (int nt = 0; nt < 2; ++nt)
        acc[mt][nt] = __builtin_amdgcn_mfma_f32_32x32x16_bf16(
            fah[cb][mt], fbh[cb][nt], acc[mt][nt], 0, 0, 0);
#pragma unroll
    for (int mt = 0; mt < 2; ++mt)
#pragma unroll
      for (int nt = 0; nt < 2; ++nt)
        acc[mt][nt] = __builtin_amdgcn_mfma_f32_32x32x16_bf16(
            fah[cb][mt], fbl[cb][nt], acc[mt][nt], 0, 0, 0);
#pragma unroll
    for (int mt = 0; mt < 2; ++mt)
#pragma unroll
      for (int nt = 0; nt < 2; ++nt)
        acc[mt][nt] = __builtin_amdgcn_mfma_f32_32x32x16_bf16(
            fal[cb][mt], fbh[cb][nt], acc[mt][nt], 0, 0, 0);
  }
  if (is_h) {
#pragma unroll
    for (int mt = 0; mt < 2; ++mt)
#pragma unroll
      for (int nt = 0; nt < 2; ++nt) {
        int col = cbase + wn * 64 + nt * 32 + lm;
#pragma unroll
        for (int r = 0; r < 16; ++r) {
          int row =
              rbase + wm * 64 + mt * 32 + (r & 3) + 8 * (r >> 2) + 4 * lkh;
          h[(size_t)row * O_DIM + col] = acc[mt][nt][r];
        }
      }
  } else {
    const float beta = beta_p[0];
    const float ombeta = 1.0f - beta;
#pragma unroll
    for (int mt = 0; mt < 2; ++mt)
#pragma unroll
      for (int nt = 0; nt < 2; ++nt) {
        int col = cbase + wn * 64 + nt * 32 + lm;
#pragma unroll
        for (int r = 0; r < 16; ++r) {
          int row =
              rbase + wm * 64 + mt * 32 + (r & 3) + 8 * (r >> 2) + 4 * lkh;
          M[(size_t)row * O_DIM + col] =
              ombeta * v[(size_t)row * O_DIM + col] - beta * acc[mt][nt][r];
        }
      }
  }
}

// ---------------------------------------------------------------------------
// Scan: ONE WAVE per batch (64 threads), 16 neurons/lane, BARRIER-FREE.
// Spike sets live in 16 wave-uniform ballot masks (registers, no LDS).
// Lateral gather: scalar loop over set bits, all lanes load M row slices.
// Folded finalize: last WG (device done counter) reduces wgcnt.
// Neuron o = 256*k + 4*lane + j  (k,j in 0..3) -> all h/out/M accesses are
// coalesced float4.
// ---------------------------------------------------------------------------
__global__ __launch_bounds__(64) void scan_kernel(
    const float* __restrict__ h, const float* __restrict__ M,
    const double* __restrict__ normpart, const float* __restrict__ bvec,
    const float* __restrict__ beta_p, float* __restrict__ out,
    int* __restrict__ wgcnt, int* __restrict__ done) {
  const int b = blockIdx.x, lane = threadIdx.x;
  const double beta = (double)beta_p[0];
  const double ombeta = 1.0 - beta;
  double mem[4][4], inv[4][4], bth[4][4];
  unsigned long long pmask[4][4];
#pragma unroll
  for (int k = 0; k < 4; ++k)
#pragma unroll
    for (int j = 0; j < 4; ++j) {
      const int o = 256 * k + 4 * lane + j;
      mem[k][j] = 0.0;
      double s = 0.0;
#pragma unroll
      for (int g = 0; g < 16; ++g) s += normpart[(size_t)g * O_DIM + o];
      inv[k][j] = 1.0 / (s + 1e-8);
      bth[k][j] = (double)bvec[o];
      pmask[k][j] = 0ull;
    }
  const float* hb = h + (size_t)b * T_DIM * O_DIM;
  float* obp = out + (size_t)b * T_DIM * O_DIM;
  float4 hv0[4], hv1[4];
#pragma unroll
  for (int k = 0; k < 4; ++k) {
    hv0[k] = *(const float4*)&hb[256 * k + 4 * lane];
    hv1[k] = *(const float4*)&hb[O_DIM + 256 * k + 4 * lane];
  }
  int total = 0;
  for (int t = 0; t < T_DIM; ++t) {
    float4 hv2[4];
#pragma unroll
    for (int k = 0; k < 4; ++k) hv2[k] = make_float4(0.f, 0.f, 0.f, 0.f);
    if (t + 2 < T_DIM) {
#pragma unroll
      for (int k = 0; k < 4; ++k)
        hv2[k] = *(const float4*)&hb[(size_t)(t + 2) * O_DIM + 256 * k +
                                     4 * lane];
    }
    double lat[4][4] = {};
#pragma unroll
    for (int k2 = 0; k2 < 4; ++k2)
#pragma unroll
      for (int j2 = 0; j2 < 4; ++j2) {
        unsigned long long m = pmask[k2][j2];
        while (m) {
          const int p = (int)__builtin_ctzll(m);
          m &= m - 1;
          const int i = 256 * k2 + 4 * p + j2;  // fired neuron index
          const float* Mr = M + (size_t)i * O_DIM + 4 * lane;
#pragma unroll
          for (int k = 0; k < 4; ++k) {
            float4 mv = *(const float4*)(Mr + 256 * k);
            lat[k][0] += (double)mv.x;
            lat[k][1] += (double)mv.y;
            lat[k][2] += (double)mv.z;
            lat[k][3] += (double)mv.w;
          }
        }
      }
    int cnt = 0;
#pragma unroll
    for (int k = 0; k < 4; ++k) {
      const float hvv[4] = {hv0[k].x, hv0[k].y, hv0[k].z, hv0[k].w};
      float os[4];
#pragma unroll
      for (int j = 0; j < 4; ++j) {
        mem[k][j] = mem[k][j] * beta + (double)hvv[j] * ombeta + lat[k][j];
        double mthr = mem[k][j] * inv[k][j] - bth[k][j];
        bool s = mthr > 0.0;
        os[j] = s ? 1.0f : 0.0f;
        unsigned long long mk = __ballot(s);
        pmask[k][j] = mk;
        cnt += (int)__popcll(mk);
      }
      *(float4*)&obp[(size_t)t * O_DIM + 256 * k + 4 * lane] =
          make_float4(os[0], os[1], os[2], os[3]);
      hv0[k] = hv1[k];
      hv1[k] = hv2[k];
    }
    total += 0;  // cnt is wave-uniform
    if (lane == 0) wgcnt[b * T_DIM + t] = cnt;
  }
  // ---- folded finalize ----
  __threadfence();
  int old = 0;
  if (lane == 0) old = atomicAdd(done, 1);
  old = __shfl(old, 0, 64);
  if (old == B_DIM - 1) {
    __threadfence();
    long long tsum = 0;
    int mx = 0;
    for (int t = lane; t < T_DIM; t += 64) {
      int st = 0;
      for (int bb = 0; bb < B_DIM; ++bb) st += wgcnt[bb * T_DIM + t];
      tsum += st;
      if (st > mx) mx = st;
    }
#pragma unroll
    for (int off = 32; off > 0; off >>= 1) {
      tsum += __shfl_down((long long)tsum, off, 64);
      int m2 = __shfl_down(mx, off, 64);
      if (m2 > mx) mx = m2;
    }
    if (lane == 0) {
      const double N = (double)B_DIM * T_DIM * O_DIM;
      out[(size_t)B_DIM * T_DIM * O_DIM] = (float)(0.5 * (double)tsum / N);
      out[(size_t)B_DIM * T_DIM * O_DIM + 1] =
          (float)((double)mx / (double)(B_DIM * O_DIM));
    }
  }
}

extern "C" void kernel_launch(void* const* d_in, const int* in_sizes, int n_in,
                              void* d_out, int out_size, void* d_ws,
                              size_t ws_size, hipStream_t stream) {
  const float* x = (const float*)d_in[0];
  const float* w = (const float*)d_in[1];
  const float* v = (const float*)d_in[2];
  const float* beta = (const float*)d_in[3];
  const float* b = (const float*)d_in[4];
  float* out = (float*)d_out;

  char* ws = (char*)d_ws;
  const size_t OFF_M = 0;            // 4 MB
  const size_t OFF_H = 4194304;      // 50 MB
  const size_t OFF_WTH = 56623104;   // 2 MB
  const size_t OFF_WTL = 58720256;   // 2 MB
  const size_t OFF_NP = 60817408;    // 128 KB normpart
  const size_t OFF_DONE = 60948480;  // 512 B done counter
  const size_t OFF_XTH = 60948992;   // 25 MB
  const size_t OFF_XTL = 87163392;   // 25 MB -> end 113377792 (fits, proven)
  float* M = (float*)(ws + OFF_M);
  float* h = (float*)(ws + OFF_H);
  unsigned short* wTth = (unsigned short*)(ws + OFF_WTH);
  unsigned short* wTtl = (unsigned short*)(ws + OFF_WTL);
  double* normpart = (double*)(ws + OFF_NP);
  int* done = (int*)(ws + OFF_DONE);
  unsigned short* xth = (unsigned short*)(ws + OFF_XTH);
  unsigned short* xtl = (unsigned short*)(ws + OFF_XTL);
  int* wgcnt = (int*)(ws + OFF_XTH);  // reuses dead xt region

  hipMemsetAsync(done, 0, 512, stream);
  hipLaunchKernelGGL(prep_kernel, dim3(1856), dim3(256), 0, stream, w, x, wTth,
                     wTtl, xth, xtl, normpart);
  hipLaunchKernelGGL(gemm_fused, dim3(864), dim3(256), 0, stream, xth, xtl,
                     wTth, wTtl, v, beta, h, M);
  hipLaunchKernelGGL(scan_kernel, dim3(128), dim3(64), 0, stream, h, M,
                     normpart, b, beta, out, wgcnt, done);
}